// Round 1
// baseline (1090.197 us; speedup 1.0000x reference)
//
#include <hip/hip_runtime.h>
#include <math.h>

constexpr int B    = 2;
constexpr int S    = 2048;
constexpr int NH   = 16;
constexpr int HD   = 64;
constexpr int DIM  = 1024;
constexpr int INNER = 1024;   // NH*HD
constexpr int QKVN = 3072;    // 3*INNER
constexpr int NTOK = B * S;   // 4096
constexpr float EPS = 1e-5f;
constexpr float MAX_SCALE = 10.0f;

// ---------------------------------------------------------------------------
// Generic tiled fp32 GEMM: C[M][N] = A[M][K] @ W[K][N] + bias[N]
// 64x64 tile per block, 256 threads, 4x4 register tile per thread, BK=16.
// M, N multiples of 64; K multiple of 16.
// ---------------------------------------------------------------------------
__global__ __launch_bounds__(256)
void gemm_bias_kernel(const float* __restrict__ A, const float* __restrict__ W,
                      const float* __restrict__ bias, float* __restrict__ C,
                      int N, int K) {
  __shared__ float As[16][64];   // [k][m]
  __shared__ float Bs[16][64];   // [k][n]
  const int tid = threadIdx.x;
  const int tx = tid & 15, ty = tid >> 4;
  const int n0 = blockIdx.x * 64;
  const int m0 = blockIdx.y * 64;

  const int la_m = tid >> 2;          // 0..63
  const int la_k = (tid & 3) * 4;     // 0,4,8,12
  const int lb_k = tid >> 4;          // 0..15
  const int lb_n = (tid & 15) * 4;    // 0..60

  const float* Aptr = A + (size_t)(m0 + la_m) * K + la_k;
  const float* Wptr = W + (size_t)lb_k * N + n0 + lb_n;

  float acc[4][4] = {};

  for (int k0 = 0; k0 < K; k0 += 16) {
    float4 av = *(const float4*)(Aptr + k0);
    float4 bv = *(const float4*)(Wptr + (size_t)k0 * N);
    __syncthreads();   // previous tile's compute reads done
    As[la_k + 0][la_m] = av.x;
    As[la_k + 1][la_m] = av.y;
    As[la_k + 2][la_m] = av.z;
    As[la_k + 3][la_m] = av.w;
    *(float4*)&Bs[lb_k][lb_n] = bv;
    __syncthreads();
#pragma unroll
    for (int kk = 0; kk < 16; ++kk) {
      float4 a4 = *(const float4*)&As[kk][ty * 4];
      float4 b4 = *(const float4*)&Bs[kk][tx * 4];
      float ar[4] = {a4.x, a4.y, a4.z, a4.w};
      float br[4] = {b4.x, b4.y, b4.z, b4.w};
#pragma unroll
      for (int i = 0; i < 4; ++i)
#pragma unroll
        for (int j = 0; j < 4; ++j)
          acc[i][j] = fmaf(ar[i], br[j], acc[i][j]);
    }
  }

  float4 bb = *(const float4*)&bias[n0 + tx * 4];
  float brr[4] = {bb.x, bb.y, bb.z, bb.w};
#pragma unroll
  for (int i = 0; i < 4; ++i) {
    float4 o;
    o.x = acc[i][0] + brr[0];
    o.y = acc[i][1] + brr[1];
    o.z = acc[i][2] + brr[2];
    o.w = acc[i][3] + brr[3];
    *(float4*)&C[(size_t)(m0 + ty * 4 + i) * N + n0 + tx * 4] = o;
  }
}

// ---------------------------------------------------------------------------
// Per-token postprocess: RMSNorm(q,k over full INNER), norm weights, rotary,
// history key scale. In-place on qkv. One block (256 thr) per token.
// ---------------------------------------------------------------------------
__global__ __launch_bounds__(256)
void postprocess_kernel(float* __restrict__ qkv, const float* __restrict__ rot,
                        const float* __restrict__ nqw, const float* __restrict__ nkw,
                        const float* __restrict__ hks, const int* __restrict__ octx) {
  const int token = blockIdx.x;
  const int spos  = token & (S - 1);
  const int tid   = threadIdx.x;
  float* qrow = qkv + (size_t)token * QKVN;
  float* krow = qrow + INNER;
  const float* r = rot + (size_t)token * (2 * HD);

  const int e0 = tid * 4;            // 4 consecutive elements (2 rotary pairs)
  float4 qv = *(float4*)(qrow + e0);
  float4 kv = *(float4*)(krow + e0);
  float q4[4] = {qv.x, qv.y, qv.z, qv.w};
  float k4[4] = {kv.x, kv.y, kv.z, kv.w};

  float sq = 0.f, sk = 0.f;
#pragma unroll
  for (int i = 0; i < 4; ++i) { sq += q4[i] * q4[i]; sk += k4[i] * k4[i]; }
  // wave64 reduce
#pragma unroll
  for (int msk = 1; msk < 64; msk <<= 1) {
    sq += __shfl_xor(sq, msk);
    sk += __shfl_xor(sk, msk);
  }
  __shared__ float red[8];
  const int wave = tid >> 6;
  if ((tid & 63) == 0) { red[wave] = sq; red[4 + wave] = sk; }
  __syncthreads();
  sq = red[0] + red[1] + red[2] + red[3];
  sk = red[4] + red[5] + red[6] + red[7];

  const float qinv = 1.0f / sqrtf(sq * (1.0f / INNER) + EPS);
  const float kinv = 1.0f / sqrtf(sk * (1.0f / INNER) + EPS);

#pragma unroll
  for (int i = 0; i < 4; ++i) {
    q4[i] = q4[i] * qinv * nqw[e0 + i];
    k4[i] = k4[i] * kinv * nkw[e0 + i];
  }

  // rotary: within-head dim of element e0 (even, e0%4==0)
  const int d0 = e0 & (HD - 1);
  const float c0 = r[d0],     s0 = r[HD + d0 + 1];
  const float c1 = r[d0 + 2], s1 = r[HD + d0 + 3];

  float qo[4], ko[4];
  qo[0] = q4[0] * c0 - q4[1] * s0;
  qo[1] = q4[0] * s0 + q4[1] * c0;
  qo[2] = q4[2] * c1 - q4[3] * s1;
  qo[3] = q4[2] * s1 + q4[3] * c1;
  ko[0] = k4[0] * c0 - k4[1] * s0;
  ko[1] = k4[0] * s0 + k4[1] * c0;
  ko[2] = k4[2] * c1 - k4[3] * s1;
  ko[3] = k4[2] * s1 + k4[3] * c1;

  const int hist = S - octx[0];
  if (hist > 0 && spos < hist) {
    const int h = e0 >> 6;
    const float sig = 1.0f / (1.0f + expf(-hks[h]));
    const float sc = 1.0f + sig * (MAX_SCALE - 1.0f);
#pragma unroll
    for (int i = 0; i < 4; ++i) ko[i] *= sc;
  }

  *(float4*)(qrow + e0) = make_float4(qo[0], qo[1], qo[2], qo[3]);
  *(float4*)(krow + e0) = make_float4(ko[0], ko[1], ko[2], ko[3]);
}

// ---------------------------------------------------------------------------
// Flash-style fp32 attention. Block = 256 thr handles one (b,h,64-row Q tile).
// K tiles of 64 staged in LDS; online softmax; P round-trips through LDS
// (aliased with the K tile). Non-causal (full S).
// ---------------------------------------------------------------------------
__global__ __launch_bounds__(256)
void attn_kernel(const float* __restrict__ qkv, float* __restrict__ out) {
  const int bh = blockIdx.x;
  const int b = bh >> 4, h = bh & 15;
  const int q0 = blockIdx.y * 64;
  const int tid = threadIdx.x;
  const int tx = tid & 15, ty = tid >> 4;

  __shared__ float Qs[64][68];    // [d][row]   (transposed)
  __shared__ float KPs[64][68];   // phase 1: K transposed [d][kcol]; phase 2: P^T [kcol][row]
  __shared__ float Vs[64][68];    // [kcol][d]  (natural)

  const float* base = qkv + (size_t)b * S * QKVN + h * HD;

  // stage Q (transposed)
  {
    const int lrow = tid >> 4;
    const int ld = (tid & 15) * 4;
#pragma unroll
    for (int it = 0; it < 4; ++it) {
      const int row = lrow + it * 16;
      float4 v = *(const float4*)(base + (size_t)(q0 + row) * QKVN + ld);
      Qs[ld + 0][row] = v.x; Qs[ld + 1][row] = v.y;
      Qs[ld + 2][row] = v.z; Qs[ld + 3][row] = v.w;
    }
  }

  float m[4], l[4], o[4][4];
#pragma unroll
  for (int i = 0; i < 4; ++i) {
    m[i] = -INFINITY; l[i] = 0.f;
#pragma unroll
    for (int j = 0; j < 4; ++j) o[i][j] = 0.f;
  }
  const float scale = 0.125f;   // 1/sqrt(64)

  for (int kt = 0; kt < S / 64; ++kt) {
    __syncthreads();   // previous iteration's PV reads of KPs/Vs complete
    {
      const int lrow = tid >> 4;
      const int ld = (tid & 15) * 4;
#pragma unroll
      for (int it = 0; it < 4; ++it) {
        const int row = lrow + it * 16;
        const float* kp = base + INNER + (size_t)(kt * 64 + row) * QKVN;
        float4 kvv = *(const float4*)(kp + ld);
        KPs[ld + 0][row] = kvv.x; KPs[ld + 1][row] = kvv.y;
        KPs[ld + 2][row] = kvv.z; KPs[ld + 3][row] = kvv.w;
        const float* vp = base + 2 * INNER + (size_t)(kt * 64 + row) * QKVN;
        *(float4*)&Vs[row][ld] = *(const float4*)(vp + ld);
      }
    }
    __syncthreads();

    // scores: sc[i][j] = q_row(ty*4+i) . k_col(tx*4+j)
    float sc[4][4] = {};
#pragma unroll 8
    for (int d = 0; d < 64; ++d) {
      float4 qv = *(const float4*)&Qs[d][ty * 4];
      float4 kv = *(const float4*)&KPs[d][tx * 4];
      float qa[4] = {qv.x, qv.y, qv.z, qv.w};
      float ka[4] = {kv.x, kv.y, kv.z, kv.w};
#pragma unroll
      for (int i = 0; i < 4; ++i)
#pragma unroll
        for (int j = 0; j < 4; ++j)
          sc[i][j] = fmaf(qa[i], ka[j], sc[i][j]);
    }

    float ps[4][4], al[4];
#pragma unroll
    for (int i = 0; i < 4; ++i) {
#pragma unroll
      for (int j = 0; j < 4; ++j) sc[i][j] *= scale;
      float mx = fmaxf(fmaxf(sc[i][0], sc[i][1]), fmaxf(sc[i][2], sc[i][3]));
      mx = fmaxf(mx, __shfl_xor(mx, 1));
      mx = fmaxf(mx, __shfl_xor(mx, 2));
      mx = fmaxf(mx, __shfl_xor(mx, 4));
      mx = fmaxf(mx, __shfl_xor(mx, 8));
      const float mn = fmaxf(m[i], mx);
      al[i] = __expf(m[i] - mn);           // -inf -> 0 on first tile
      m[i] = mn;
      float rs = 0.f;
#pragma unroll
      for (int j = 0; j < 4; ++j) { ps[i][j] = __expf(sc[i][j] - mn); rs += ps[i][j]; }
      rs += __shfl_xor(rs, 1);
      rs += __shfl_xor(rs, 2);
      rs += __shfl_xor(rs, 4);
      rs += __shfl_xor(rs, 8);
      l[i] = l[i] * al[i] + rs;
#pragma unroll
      for (int j = 0; j < 4; ++j) o[i][j] *= al[i];
    }

    __syncthreads();   // everyone done reading KPs as K before overwriting with P
#pragma unroll
    for (int i = 0; i < 4; ++i)
#pragma unroll
      for (int j = 0; j < 4; ++j)
        KPs[tx * 4 + j][ty * 4 + i] = ps[i][j];   // P^T: [kcol][row]
    __syncthreads();

    // PV: o[i][j] += sum_kk P[row][kk] * V[kk][dcol]
#pragma unroll 8
    for (int kk = 0; kk < 64; ++kk) {
      float4 pv = *(const float4*)&KPs[kk][ty * 4];
      float4 vv = *(const float4*)&Vs[kk][tx * 4];
      float pa[4] = {pv.x, pv.y, pv.z, pv.w};
      float va[4] = {vv.x, vv.y, vv.z, vv.w};
#pragma unroll
      for (int i = 0; i < 4; ++i)
#pragma unroll
        for (int j = 0; j < 4; ++j)
          o[i][j] = fmaf(pa[i], va[j], o[i][j]);
    }
  }

  // epilogue: normalize and write out[token][h*64 + d]
#pragma unroll
  for (int i = 0; i < 4; ++i) {
    const float inv = 1.0f / l[i];
    float4 o4 = make_float4(o[i][0] * inv, o[i][1] * inv, o[i][2] * inv, o[i][3] * inv);
    const int row = q0 + ty * 4 + i;
    *(float4*)&out[(size_t)(b * S + row) * INNER + h * HD + tx * 4] = o4;
  }
}

// ---------------------------------------------------------------------------
extern "C" void kernel_launch(void* const* d_in, const int* in_sizes, int n_in,
                              void* d_out, int out_size, void* d_ws, size_t ws_size,
                              hipStream_t stream) {
  const float* hs    = (const float*)d_in[0];
  const float* rot   = (const float*)d_in[1];
  const float* w_qkv = (const float*)d_in[2];
  const float* b_qkv = (const float*)d_in[3];
  const float* nqw   = (const float*)d_in[4];
  const float* nkw   = (const float*)d_in[5];
  const float* w_out = (const float*)d_in[6];
  const float* b_out = (const float*)d_in[7];
  const float* hks   = (const float*)d_in[8];
  const int*   octx  = (const int*)d_in[9];

  float* qkv      = (float*)d_ws;                        // 4096 x 3072 fp32
  float* attn_out = qkv + (size_t)NTOK * QKVN;           // 4096 x 1024 fp32
  float* out      = (float*)d_out;

  // 1) qkv = hs @ w_qkv + b_qkv
  gemm_bias_kernel<<<dim3(QKVN / 64, NTOK / 64), 256, 0, stream>>>(
      hs, w_qkv, b_qkv, qkv, QKVN, DIM);

  // 2) rmsnorm + rotary + history scale (in place)
  postprocess_kernel<<<NTOK, 256, 0, stream>>>(qkv, rot, nqw, nkw, hks, octx);

  // 3) attention -> attn_out
  attn_kernel<<<dim3(B * NH, S / 64), 256, 0, stream>>>(qkv, attn_out);

  // 4) out = attn_out @ w_out + b_out
  gemm_bias_kernel<<<dim3(DIM / 64, NTOK / 64), 256, 0, stream>>>(
      attn_out, w_out, b_out, out, DIM, INNER);
}

// Round 3
// 299.999 us; speedup vs baseline: 3.6340x; 3.6340x over previous
//
#include <hip/hip_runtime.h>
#include <math.h>

typedef float    floatx4 __attribute__((ext_vector_type(4)));
typedef _Float16 half8   __attribute__((ext_vector_type(8)));
typedef _Float16 half4v  __attribute__((ext_vector_type(4)));

constexpr int B    = 2;
constexpr int S    = 2048;
constexpr int NH   = 16;
constexpr int HD   = 64;
constexpr int DIM  = 1024;
constexpr int INNER = 1024;
constexpr int QKVN = 3072;
constexpr int NTOK = 4096;
constexpr float EPS = 1e-5f;
constexpr float MAX_SCALE = 10.0f;

// ---------------------------------------------------------------------------
// fp32 -> fp16 elementwise convert (8 elems/thread)
// ---------------------------------------------------------------------------
__global__ __launch_bounds__(256)
void cvt_f16(const float* __restrict__ in, _Float16* __restrict__ out, int n8) {
  int id = blockIdx.x * 256 + threadIdx.x;
  if (id >= n8) return;
  const float4 a = ((const float4*)in)[id * 2];
  const float4 b = ((const float4*)in)[id * 2 + 1];
  half8 o;
  o[0] = (_Float16)a.x; o[1] = (_Float16)a.y; o[2] = (_Float16)a.z; o[3] = (_Float16)a.w;
  o[4] = (_Float16)b.x; o[5] = (_Float16)b.y; o[6] = (_Float16)b.z; o[7] = (_Float16)b.w;
  ((half8*)out)[id] = o;
}

// ---------------------------------------------------------------------------
// w [K][N] fp32  ->  wT [N][K] fp16   (64x64 tiles through LDS)
// ---------------------------------------------------------------------------
__global__ __launch_bounds__(256)
void transpose_w(const float* __restrict__ w, _Float16* __restrict__ wT, int K, int N) {
  __shared__ _Float16 T[64 * 72];
  const int k0 = blockIdx.y * 64, n0 = blockIdx.x * 64;
  const int tid = threadIdx.x;
#pragma unroll
  for (int i = 0; i < 4; ++i) {
    int id = tid + 256 * i;           // 1024 float4 chunks
    int r = id >> 4, c = id & 15;
    float4 v = *(const float4*)&w[(size_t)(k0 + r) * N + n0 + c * 4];
    half4v s; s[0] = (_Float16)v.x; s[1] = (_Float16)v.y;
    s[2] = (_Float16)v.z; s[3] = (_Float16)v.w;
    *(half4v*)&T[r * 72 + c * 4] = s;
  }
  __syncthreads();
#pragma unroll
  for (int i = 0; i < 2; ++i) {
    int id = tid + 256 * i;           // 512 half8 chunks
    int n = id >> 3, cs = id & 7;
    half8 o;
#pragma unroll
    for (int jj = 0; jj < 8; ++jj) o[jj] = T[(cs * 8 + jj) * 72 + n];
    *(half8*)&wT[(size_t)(n0 + n) * K + k0 + cs * 8] = o;
  }
}

// ---------------------------------------------------------------------------
// fp16 MFMA GEMM: C[M][N] = A[M][K] @ BT[N][K]^T + bias
// 128x128 tile, 256 thr (4 waves, 2x2), BK=32, 16x16x32 MFMA, 4x4 acc/wave.
// LDS rows padded to 56 halves (112 B: 16B-aligned, 2-way banks = free).
// ---------------------------------------------------------------------------
template<bool OUT_F16, typename OutT>
__global__ __launch_bounds__(256)
void gemm_bt(const _Float16* __restrict__ A, const _Float16* __restrict__ BT,
             const float* __restrict__ bias, OutT* __restrict__ C, int N, int K) {
  __shared__ _Float16 As[128 * 56];
  __shared__ _Float16 Bs[128 * 56];
  const int tid = threadIdx.x;
  const int wave = tid >> 6, lane = tid & 63, quad = lane >> 4, l16 = lane & 15;
  const int wm = wave >> 1, wn = wave & 1;
  const int m0 = blockIdx.y * 128, n0 = blockIdx.x * 128;

  floatx4 acc[4][4] = {};

  for (int k0 = 0; k0 < K; k0 += 32) {
    __syncthreads();
#pragma unroll
    for (int i = 0; i < 2; ++i) {
      int id = tid + 256 * i;
      int m = id >> 2, c = id & 3;
      *(half8*)&As[m * 56 + c * 8] = *(const half8*)&A[(size_t)(m0 + m) * K + k0 + c * 8];
      *(half8*)&Bs[m * 56 + c * 8] = *(const half8*)&BT[(size_t)(n0 + m) * K + k0 + c * 8];
    }
    __syncthreads();
    half8 a[4], b[4];
#pragma unroll
    for (int i = 0; i < 4; ++i)
      a[i] = *(const half8*)&As[(wm * 64 + i * 16 + l16) * 56 + quad * 8];
#pragma unroll
    for (int j = 0; j < 4; ++j)
      b[j] = *(const half8*)&Bs[(wn * 64 + j * 16 + l16) * 56 + quad * 8];
#pragma unroll
    for (int i = 0; i < 4; ++i)
#pragma unroll
      for (int j = 0; j < 4; ++j)
        acc[i][j] = __builtin_amdgcn_mfma_f32_16x16x32_f16(a[i], b[j], acc[i][j], 0, 0, 0);
  }

  const int rb = m0 + wm * 64 + quad * 4;
  const int cb = n0 + wn * 64 + l16;
#pragma unroll
  for (int j = 0; j < 4; ++j) {
    const float bj = bias[cb + j * 16];
#pragma unroll
    for (int i = 0; i < 4; ++i) {
#pragma unroll
      for (int r = 0; r < 4; ++r) {
        float v = acc[i][j][r] + bj;
        size_t idx = (size_t)(rb + i * 16 + r) * N + cb + j * 16;
        if constexpr (OUT_F16) C[idx] = (_Float16)v; else C[idx] = v;
      }
    }
  }
}

// ---------------------------------------------------------------------------
// Postprocess: RMSNorm(q,k over INNER) + weights + rotary + history scale.
// Reads qkvh fp16 [token][3072]; writes qh/kh fp16 [b][h][s][d].
// ---------------------------------------------------------------------------
__global__ __launch_bounds__(256)
void postprocess(const _Float16* __restrict__ qkvh, const float* __restrict__ rot,
                 const float* __restrict__ nqw, const float* __restrict__ nkw,
                 const float* __restrict__ hks, const int* __restrict__ octx,
                 _Float16* __restrict__ qo_, _Float16* __restrict__ ko_) {
  const int token = blockIdx.x;
  const int b = token >> 11, spos = token & (S - 1);
  const int tid = threadIdx.x;
  const _Float16* qrow = qkvh + (size_t)token * QKVN;
  const _Float16* krow = qrow + INNER;
  const float* r = rot + (size_t)token * (2 * HD);

  const int e0 = tid * 4;
  half4v qs = *(const half4v*)(qrow + e0);
  half4v ks = *(const half4v*)(krow + e0);
  float q4[4], k4[4];
#pragma unroll
  for (int i = 0; i < 4; ++i) { q4[i] = (float)qs[i]; k4[i] = (float)ks[i]; }

  float sq = 0.f, sk = 0.f;
#pragma unroll
  for (int i = 0; i < 4; ++i) { sq += q4[i] * q4[i]; sk += k4[i] * k4[i]; }
#pragma unroll
  for (int msk = 1; msk < 64; msk <<= 1) {
    sq += __shfl_xor(sq, msk);
    sk += __shfl_xor(sk, msk);
  }
  __shared__ float red[8];
  const int wv = tid >> 6;
  if ((tid & 63) == 0) { red[wv] = sq; red[4 + wv] = sk; }
  __syncthreads();
  sq = red[0] + red[1] + red[2] + red[3];
  sk = red[4] + red[5] + red[6] + red[7];

  const float qinv = 1.0f / sqrtf(sq * (1.0f / INNER) + EPS);
  const float kinv = 1.0f / sqrtf(sk * (1.0f / INNER) + EPS);

#pragma unroll
  for (int i = 0; i < 4; ++i) {
    q4[i] = q4[i] * qinv * nqw[e0 + i];
    k4[i] = k4[i] * kinv * nkw[e0 + i];
  }

  const int h = e0 >> 6, d0 = e0 & (HD - 1);
  const float c0 = r[d0],     s0 = r[HD + d0 + 1];
  const float c1 = r[d0 + 2], s1 = r[HD + d0 + 3];

  float qo[4], ko[4];
  qo[0] = q4[0] * c0 - q4[1] * s0;
  qo[1] = q4[0] * s0 + q4[1] * c0;
  qo[2] = q4[2] * c1 - q4[3] * s1;
  qo[3] = q4[2] * s1 + q4[3] * c1;
  ko[0] = k4[0] * c0 - k4[1] * s0;
  ko[1] = k4[0] * s0 + k4[1] * c0;
  ko[2] = k4[2] * c1 - k4[3] * s1;
  ko[3] = k4[2] * s1 + k4[3] * c1;

  const int hist = S - octx[0];
  if (hist > 0 && spos < hist) {
    const float sig = 1.0f / (1.0f + expf(-hks[h]));
    const float sc = 1.0f + sig * (MAX_SCALE - 1.0f);
#pragma unroll
    for (int i = 0; i < 4; ++i) ko[i] *= sc;
  }

  half4v qo4, ko4;
#pragma unroll
  for (int i = 0; i < 4; ++i) { qo4[i] = (_Float16)qo[i]; ko4[i] = (_Float16)ko[i]; }
  const size_t obase = ((size_t)(b * NH + h) * S + spos) * HD + d0;
  *(half4v*)(qo_ + obase) = qo4;
  *(half4v*)(ko_ + obase) = ko4;
}

// ---------------------------------------------------------------------------
// V slice of qkvh -> vT fp16 [b][h][d][s]  (64x64 transpose tiles)
// ---------------------------------------------------------------------------
__global__ __launch_bounds__(256)
void prep_vT(const _Float16* __restrict__ qkvh, _Float16* __restrict__ vt) {
  __shared__ _Float16 T[64 * 72];
  const int bh = blockIdx.x;
  const int b = bh >> 4, h = bh & 15;
  const int s0 = blockIdx.y * 64;
  const int tid = threadIdx.x;
#pragma unroll
  for (int i = 0; i < 2; ++i) {
    int id = tid + 256 * i;
    int s = id >> 3, c = id & 7;
    *(half8*)&T[s * 72 + c * 8] =
        *(const half8*)&qkvh[(size_t)(b * S + s0 + s) * QKVN + 2 * INNER + h * HD + c * 8];
  }
  __syncthreads();
#pragma unroll
  for (int i = 0; i < 2; ++i) {
    int id = tid + 256 * i;
    int d = id >> 3, cs = id & 7;
    half8 o;
#pragma unroll
    for (int jj = 0; jj < 8; ++jj) o[jj] = T[(cs * 8 + jj) * 72 + d];
    *(half8*)&vt[((size_t)bh * HD + d) * S + s0 + cs * 8] = o;
  }
}

// ---------------------------------------------------------------------------
// MFMA flash attention (fp16). Block = 4 waves = one (b,h, 64-row Q tile).
// Wave w owns q-rows w*16..w*16+15. K/Vt tiles of 64 staged in LDS.
// P round-trips through LDS (wave-private rows -> no barrier needed).
// ---------------------------------------------------------------------------
__global__ __launch_bounds__(256)
void attn_mfma(const _Float16* __restrict__ qb, const _Float16* __restrict__ kb,
               const _Float16* __restrict__ vt, _Float16* __restrict__ out) {
  __shared__ _Float16 Qs[64 * 72], Ks[64 * 72], Vs[64 * 72], Ps[64 * 72];
  const int bh = blockIdx.x;
  const int b = bh >> 4, h = bh & 15;
  const int q0 = blockIdx.y * 64;
  const int tid = threadIdx.x;
  const int wave = tid >> 6, lane = tid & 63, quad = lane >> 4, l16 = lane & 15;

  const _Float16* qbh = qb + (size_t)bh * S * HD;
  const _Float16* kbh = kb + (size_t)bh * S * HD;
  const _Float16* vbh = vt + (size_t)bh * HD * S;

#pragma unroll
  for (int i = 0; i < 2; ++i) {
    int id = tid + 256 * i;
    int rr = id >> 3, c = id & 7;
    *(half8*)&Qs[rr * 72 + c * 8] = *(const half8*)&qbh[(size_t)(q0 + rr) * HD + c * 8];
  }

  floatx4 o[4] = {};
  float mrow[4], lrow[4];
#pragma unroll
  for (int r = 0; r < 4; ++r) { mrow[r] = -INFINITY; lrow[r] = 0.f; }

  for (int kt = 0; kt < S / 64; ++kt) {
    __syncthreads();
#pragma unroll
    for (int i = 0; i < 2; ++i) {
      int id = tid + 256 * i;
      int rr = id >> 3, c = id & 7;
      *(half8*)&Ks[rr * 72 + c * 8] = *(const half8*)&kbh[(size_t)(kt * 64 + rr) * HD + c * 8];
      *(half8*)&Vs[rr * 72 + c * 8] = *(const half8*)&vbh[(size_t)rr * S + kt * 64 + c * 8];
    }
    __syncthreads();

    // S = Q @ K^T   (A: Qs rows, B: Ks rows; k-dim = d, 2 steps of 32)
    floatx4 sc[4] = {};
    half8 aq[2];
#pragma unroll
    for (int ks = 0; ks < 2; ++ks)
      aq[ks] = *(const half8*)&Qs[(wave * 16 + l16) * 72 + ks * 32 + quad * 8];
#pragma unroll
    for (int j = 0; j < 4; ++j) {
#pragma unroll
      for (int ks = 0; ks < 2; ++ks) {
        half8 bk = *(const half8*)&Ks[(j * 16 + l16) * 72 + ks * 32 + quad * 8];
        sc[j] = __builtin_amdgcn_mfma_f32_16x16x32_f16(aq[ks], bk, sc[j], 0, 0, 0);
      }
    }

    // online softmax; lane holds S[row=quad*4+r][col=j*16+l16]
    float p[4][4], alpha[4];
#pragma unroll
    for (int r = 0; r < 4; ++r) {
      float mx = -INFINITY;
#pragma unroll
      for (int j = 0; j < 4; ++j) { sc[j][r] *= 0.125f; mx = fmaxf(mx, sc[j][r]); }
      mx = fmaxf(mx, __shfl_xor(mx, 1));
      mx = fmaxf(mx, __shfl_xor(mx, 2));
      mx = fmaxf(mx, __shfl_xor(mx, 4));
      mx = fmaxf(mx, __shfl_xor(mx, 8));
      const float mn = fmaxf(mrow[r], mx);
      alpha[r] = __expf(mrow[r] - mn);
      mrow[r] = mn;
      float rs = 0.f;
#pragma unroll
      for (int j = 0; j < 4; ++j) { p[j][r] = __expf(sc[j][r] - mn); rs += p[j][r]; }
      rs += __shfl_xor(rs, 1); rs += __shfl_xor(rs, 2);
      rs += __shfl_xor(rs, 4); rs += __shfl_xor(rs, 8);
      lrow[r] = lrow[r] * alpha[r] + rs;
    }
#pragma unroll
    for (int j = 0; j < 4; ++j)
#pragma unroll
      for (int r = 0; r < 4; ++r)
        o[j][r] *= alpha[r];

    // P -> LDS in A-operand layout (wave-private rows)
#pragma unroll
    for (int j = 0; j < 4; ++j)
#pragma unroll
      for (int r = 0; r < 4; ++r)
        Ps[(wave * 16 + quad * 4 + r) * 72 + j * 16 + l16] = (_Float16)p[j][r];

    // O += P @ V   (A: Ps rows, B: Vs rows (V^T); k-dim = kcol, 2 steps)
    half8 ap[2];
#pragma unroll
    for (int ks = 0; ks < 2; ++ks)
      ap[ks] = *(const half8*)&Ps[(wave * 16 + l16) * 72 + ks * 32 + quad * 8];
#pragma unroll
    for (int j = 0; j < 4; ++j) {
#pragma unroll
      for (int ks = 0; ks < 2; ++ks) {
        half8 bv = *(const half8*)&Vs[(j * 16 + l16) * 72 + ks * 32 + quad * 8];
        o[j] = __builtin_amdgcn_mfma_f32_16x16x32_f16(ap[ks], bv, o[j], 0, 0, 0);
      }
    }
  }

#pragma unroll
  for (int r = 0; r < 4; ++r) {
    const float inv = 1.0f / lrow[r];
    const int row = q0 + wave * 16 + quad * 4 + r;
#pragma unroll
    for (int j = 0; j < 4; ++j)
      out[(size_t)(b * S + row) * INNER + h * HD + j * 16 + l16] =
          (_Float16)(o[j][r] * inv);
  }
}

// ---------------------------------------------------------------------------
extern "C" void kernel_launch(void* const* d_in, const int* in_sizes, int n_in,
                              void* d_out, int out_size, void* d_ws, size_t ws_size,
                              hipStream_t stream) {
  const float* hs    = (const float*)d_in[0];
  const float* rot   = (const float*)d_in[1];
  const float* w_qkv = (const float*)d_in[2];
  const float* b_qkv = (const float*)d_in[3];
  const float* nqw   = (const float*)d_in[4];
  const float* nkw   = (const float*)d_in[5];
  const float* w_out = (const float*)d_in[6];
  const float* b_out = (const float*)d_in[7];
  const float* hks   = (const float*)d_in[8];
  const int*   octx  = (const int*)d_in[9];

  _Float16* hsb   = (_Float16*)d_ws;                 // 4096x1024 f16 (8 MiB)
  _Float16* attnb = hsb;                             // alias: hsb dead after QKV GEMM
  _Float16* wqkvT = hsb   + (size_t)NTOK * DIM;      // 3072x1024 (6 MiB)
  _Float16* woutT = wqkvT + (size_t)QKVN * DIM;      // 1024x1024 (2 MiB)
  _Float16* qkvh  = woutT + (size_t)DIM * INNER;     // 4096x3072 (24 MiB)
  _Float16* q_h   = qkvh  + (size_t)NTOK * QKVN;     // [2][16][2048][64] (8 MiB)
  _Float16* k_h   = q_h   + (size_t)B * NH * S * HD; // (8 MiB)
  _Float16* vT    = k_h   + (size_t)B * NH * S * HD; // [2][16][64][2048] (8 MiB)

  // prep: convert hs, transpose+convert weights
  cvt_f16<<<(NTOK * DIM / 8 + 255) / 256, 256, 0, stream>>>(hs, hsb, NTOK * DIM / 8);
  transpose_w<<<dim3(QKVN / 64, DIM / 64), 256, 0, stream>>>(w_qkv, wqkvT, DIM, QKVN);
  transpose_w<<<dim3(DIM / 64, INNER / 64), 256, 0, stream>>>(w_out, woutT, INNER, DIM);

  // 1) qkvh = hsb @ wqkvT^T + b_qkv  (f16 out)
  gemm_bt<true, _Float16><<<dim3(QKVN / 128, NTOK / 128), 256, 0, stream>>>(
      hsb, wqkvT, b_qkv, qkvh, QKVN, DIM);

  // 2) rmsnorm + rotary + history scale -> q_h, k_h ; transpose v -> vT
  postprocess<<<NTOK, 256, 0, stream>>>(qkvh, rot, nqw, nkw, hks, octx, q_h, k_h);
  prep_vT<<<dim3(B * NH, S / 64), 256, 0, stream>>>(qkvh, vT);

  // 3) attention -> attnb (f16)
  attn_mfma<<<dim3(B * NH, S / 64), 256, 0, stream>>>(q_h, k_h, vT, attnb);

  // 4) out = attnb @ woutT^T + b_out  (fp32 out)
  gemm_bt<false, float><<<dim3(DIM / 128, NTOK / 128), 256, 0, stream>>>(
      attnb, woutT, b_out, (float*)d_out, DIM, INNER);
}

// Round 5
// 258.780 us; speedup vs baseline: 4.2128x; 1.1593x over previous
//
#include <hip/hip_runtime.h>
#include <math.h>

typedef float    floatx4 __attribute__((ext_vector_type(4)));
typedef _Float16 half8   __attribute__((ext_vector_type(8)));
typedef _Float16 half4v  __attribute__((ext_vector_type(4)));

constexpr int B    = 2;
constexpr int S    = 2048;
constexpr int NH   = 16;
constexpr int HD   = 64;
constexpr int DIM  = 1024;
constexpr int INNER = 1024;
constexpr int QKVN = 3072;
constexpr int NTOK = 4096;
constexpr float EPS = 1e-5f;
constexpr float MAX_SCALE = 10.0f;
// softmax scale 1/sqrt(64) folded with log2(e) into q at postprocess time
constexpr float SCALE_LOG2E = 0.125f * 1.4426950408889634f;

// Legacy K=16 MFMA uses the concatenated CDNA1-era name (no underscore).
#define MFMA16(a, b, c) __builtin_amdgcn_mfma_f32_16x16x16f16((a), (b), (c), 0, 0, 0)

// ---------------------------------------------------------------------------
// fp32 -> fp16 elementwise convert (8 elems/thread)
// ---------------------------------------------------------------------------
__global__ __launch_bounds__(256)
void cvt_f16(const float* __restrict__ in, _Float16* __restrict__ out, int n8) {
  int id = blockIdx.x * 256 + threadIdx.x;
  if (id >= n8) return;
  const float4 a = ((const float4*)in)[id * 2];
  const float4 b = ((const float4*)in)[id * 2 + 1];
  half8 o;
  o[0] = (_Float16)a.x; o[1] = (_Float16)a.y; o[2] = (_Float16)a.z; o[3] = (_Float16)a.w;
  o[4] = (_Float16)b.x; o[5] = (_Float16)b.y; o[6] = (_Float16)b.z; o[7] = (_Float16)b.w;
  ((half8*)out)[id] = o;
}

// ---------------------------------------------------------------------------
// w [K][N] fp32  ->  wT [N][K] fp16   (64x64 tiles through LDS)
// ---------------------------------------------------------------------------
__global__ __launch_bounds__(256)
void transpose_w(const float* __restrict__ w, _Float16* __restrict__ wT, int K, int N) {
  __shared__ _Float16 T[64 * 72];
  const int k0 = blockIdx.y * 64, n0 = blockIdx.x * 64;
  const int tid = threadIdx.x;
#pragma unroll
  for (int i = 0; i < 4; ++i) {
    int id = tid + 256 * i;
    int r = id >> 4, c = id & 15;
    float4 v = *(const float4*)&w[(size_t)(k0 + r) * N + n0 + c * 4];
    half4v s; s[0] = (_Float16)v.x; s[1] = (_Float16)v.y;
    s[2] = (_Float16)v.z; s[3] = (_Float16)v.w;
    *(half4v*)&T[r * 72 + c * 4] = s;
  }
  __syncthreads();
#pragma unroll
  for (int i = 0; i < 2; ++i) {
    int id = tid + 256 * i;
    int n = id >> 3, cs = id & 7;
    half8 o;
#pragma unroll
    for (int jj = 0; jj < 8; ++jj) o[jj] = T[(cs * 8 + jj) * 72 + n];
    *(half8*)&wT[(size_t)(n0 + n) * K + k0 + cs * 8] = o;
  }
}

// ---------------------------------------------------------------------------
// fp16 MFMA GEMM: C[M][N] = A[M][K] @ BT[N][K]^T + bias  (unchanged from R3)
// ---------------------------------------------------------------------------
template<bool OUT_F16, typename OutT>
__global__ __launch_bounds__(256)
void gemm_bt(const _Float16* __restrict__ A, const _Float16* __restrict__ BT,
             const float* __restrict__ bias, OutT* __restrict__ C, int N, int K) {
  __shared__ _Float16 As[128 * 56];
  __shared__ _Float16 Bs[128 * 56];
  const int tid = threadIdx.x;
  const int wave = tid >> 6, lane = tid & 63, quad = lane >> 4, l16 = lane & 15;
  const int wm = wave >> 1, wn = wave & 1;
  const int m0 = blockIdx.y * 128, n0 = blockIdx.x * 128;

  floatx4 acc[4][4] = {};

  for (int k0 = 0; k0 < K; k0 += 32) {
    __syncthreads();
#pragma unroll
    for (int i = 0; i < 2; ++i) {
      int id = tid + 256 * i;
      int m = id >> 2, c = id & 3;
      *(half8*)&As[m * 56 + c * 8] = *(const half8*)&A[(size_t)(m0 + m) * K + k0 + c * 8];
      *(half8*)&Bs[m * 56 + c * 8] = *(const half8*)&BT[(size_t)(n0 + m) * K + k0 + c * 8];
    }
    __syncthreads();
    half8 a[4], b[4];
#pragma unroll
    for (int i = 0; i < 4; ++i)
      a[i] = *(const half8*)&As[(wm * 64 + i * 16 + l16) * 56 + quad * 8];
#pragma unroll
    for (int j = 0; j < 4; ++j)
      b[j] = *(const half8*)&Bs[(wn * 64 + j * 16 + l16) * 56 + quad * 8];
#pragma unroll
    for (int i = 0; i < 4; ++i)
#pragma unroll
      for (int j = 0; j < 4; ++j)
        acc[i][j] = __builtin_amdgcn_mfma_f32_16x16x32_f16(a[i], b[j], acc[i][j], 0, 0, 0);
  }

  const int rb = m0 + wm * 64 + quad * 4;
  const int cb = n0 + wn * 64 + l16;
#pragma unroll
  for (int j = 0; j < 4; ++j) {
    const float bj = bias[cb + j * 16];
#pragma unroll
    for (int i = 0; i < 4; ++i) {
#pragma unroll
      for (int r = 0; r < 4; ++r) {
        float v = acc[i][j][r] + bj;
        size_t idx = (size_t)(rb + i * 16 + r) * N + cb + j * 16;
        if constexpr (OUT_F16) C[idx] = (_Float16)v; else C[idx] = v;
      }
    }
  }
}

// ---------------------------------------------------------------------------
// Postprocess: RMSNorm(q,k over INNER) + weights + rotary + history scale.
// q additionally pre-scaled by 0.125*log2(e) so attention scores are in
// log2-domain and softmax uses exp2 with no per-score scale mul.
// ---------------------------------------------------------------------------
__global__ __launch_bounds__(256)
void postprocess(const _Float16* __restrict__ qkvh, const float* __restrict__ rot,
                 const float* __restrict__ nqw, const float* __restrict__ nkw,
                 const float* __restrict__ hks, const int* __restrict__ octx,
                 _Float16* __restrict__ qo_, _Float16* __restrict__ ko_) {
  const int token = blockIdx.x;
  const int b = token >> 11, spos = token & (S - 1);
  const int tid = threadIdx.x;
  const _Float16* qrow = qkvh + (size_t)token * QKVN;
  const _Float16* krow = qrow + INNER;
  const float* r = rot + (size_t)token * (2 * HD);

  const int e0 = tid * 4;
  half4v qs = *(const half4v*)(qrow + e0);
  half4v ks = *(const half4v*)(krow + e0);
  float q4[4], k4[4];
#pragma unroll
  for (int i = 0; i < 4; ++i) { q4[i] = (float)qs[i]; k4[i] = (float)ks[i]; }

  float sq = 0.f, sk = 0.f;
#pragma unroll
  for (int i = 0; i < 4; ++i) { sq += q4[i] * q4[i]; sk += k4[i] * k4[i]; }
#pragma unroll
  for (int msk = 1; msk < 64; msk <<= 1) {
    sq += __shfl_xor(sq, msk);
    sk += __shfl_xor(sk, msk);
  }
  __shared__ float red[8];
  const int wv = tid >> 6;
  if ((tid & 63) == 0) { red[wv] = sq; red[4 + wv] = sk; }
  __syncthreads();
  sq = red[0] + red[1] + red[2] + red[3];
  sk = red[4] + red[5] + red[6] + red[7];

  const float qinv = 1.0f / sqrtf(sq * (1.0f / INNER) + EPS);
  const float kinv = 1.0f / sqrtf(sk * (1.0f / INNER) + EPS);

#pragma unroll
  for (int i = 0; i < 4; ++i) {
    q4[i] = q4[i] * qinv * nqw[e0 + i];
    k4[i] = k4[i] * kinv * nkw[e0 + i];
  }

  const int h = e0 >> 6, d0 = e0 & (HD - 1);
  const float c0 = r[d0],     s0 = r[HD + d0 + 1];
  const float c1 = r[d0 + 2], s1 = r[HD + d0 + 3];

  float qo[4], ko[4];
  qo[0] = q4[0] * c0 - q4[1] * s0;
  qo[1] = q4[0] * s0 + q4[1] * c0;
  qo[2] = q4[2] * c1 - q4[3] * s1;
  qo[3] = q4[2] * s1 + q4[3] * c1;
  ko[0] = k4[0] * c0 - k4[1] * s0;
  ko[1] = k4[0] * s0 + k4[1] * c0;
  ko[2] = k4[2] * c1 - k4[3] * s1;
  ko[3] = k4[2] * s1 + k4[3] * c1;

  const int hist = S - octx[0];
  if (hist > 0 && spos < hist) {
    const float sig = 1.0f / (1.0f + expf(-hks[h]));
    const float sc = 1.0f + sig * (MAX_SCALE - 1.0f);
#pragma unroll
    for (int i = 0; i < 4; ++i) ko[i] *= sc;
  }

  half4v qo4, ko4;
#pragma unroll
  for (int i = 0; i < 4; ++i) {
    qo4[i] = (_Float16)(qo[i] * SCALE_LOG2E);
    ko4[i] = (_Float16)ko[i];
  }
  const size_t obase = ((size_t)(b * NH + h) * S + spos) * HD + d0;
  *(half4v*)(qo_ + obase) = qo4;
  *(half4v*)(ko_ + obase) = ko4;
}

// ---------------------------------------------------------------------------
// V slice of qkvh -> vT fp16 swizzled for x16 B-frags:
// vt[bh][kt][d][pos], pos(s_local = jj*16+quad*4+i) = quad*16 + jj*4 + i.
// (pos = 4*g over write groups g -> contiguous coalesced stores.)
// ---------------------------------------------------------------------------
__global__ __launch_bounds__(256)
void prep_vT(const _Float16* __restrict__ qkvh, _Float16* __restrict__ vt) {
  __shared__ _Float16 T[64 * 72];
  const int bh = blockIdx.x;
  const int b = bh >> 4, h = bh & 15;
  const int kt = blockIdx.y;
  const int s0 = kt * 64;
  const int tid = threadIdx.x;
#pragma unroll
  for (int i = 0; i < 2; ++i) {
    int id = tid + 256 * i;
    int s = id >> 3, c = id & 7;
    *(half8*)&T[s * 72 + c * 8] =
        *(const half8*)&qkvh[(size_t)(b * S + s0 + s) * QKVN + 2 * INNER + h * HD + c * 8];
  }
  __syncthreads();
  _Float16* orow = vt + ((size_t)bh * 32 + kt) * 64 * 64;
#pragma unroll
  for (int i = 0; i < 4; ++i) {
    int id = tid + 256 * i;             // 1024 half4 groups
    int d = id >> 4, g = id & 15;
    int quad = g >> 2, jj = g & 3;
    half4v o;
#pragma unroll
    for (int k = 0; k < 4; ++k) o[k] = T[(jj * 16 + quad * 4 + k) * 72 + d];
    *(half4v*)&orow[d * 64 + g * 4] = o;   // pos = quad*16+jj*4 = 4*g
  }
}

// ---------------------------------------------------------------------------
// MFMA flash attention, S^T formulation.
// Block = 4 waves = one (b,h, 64-row Q tile); wave owns 16 Q rows.
// QK^T computed transposed (A=K, B=Q) so each lane's score frag holds one
// Q row -> P feeds PV 16x16x16 MFMAs directly from registers (no LDS P).
// ---------------------------------------------------------------------------
__global__ __launch_bounds__(256)
void attn_mfma(const _Float16* __restrict__ qb, const _Float16* __restrict__ kb,
               const _Float16* __restrict__ vt, _Float16* __restrict__ out) {
  __shared__ _Float16 Ks[64 * 72];   // [kcol][d]
  __shared__ _Float16 Vs[64 * 72];   // [d][pos] swizzled
  const int bh = blockIdx.x;
  const int b = bh >> 4, h = bh & 15;
  const int q0 = blockIdx.y * 64;
  const int tid = threadIdx.x;
  const int wave = tid >> 6, lane = tid & 63, quad = lane >> 4, l16 = lane & 15;

  const _Float16* qbh = qb + (size_t)bh * S * HD;
  const _Float16* kbh = kb + (size_t)bh * S * HD;
  const _Float16* vbh = vt + (size_t)bh * S * HD;   // swizzled [kt][d][pos]

  // Q fragments (B-operand for the S^T MFMA), loaded once from global.
  half8 aq[2];
#pragma unroll
  for (int ks = 0; ks < 2; ++ks)
    aq[ks] = *(const half8*)&qbh[(size_t)(q0 + wave * 16 + l16) * HD + ks * 32 + quad * 8];

  floatx4 o16[4] = {};
  float mrow = -INFINITY, lrow = 0.f;

  for (int kt = 0; kt < S / 64; ++kt) {
    __syncthreads();
#pragma unroll
    for (int i = 0; i < 2; ++i) {
      int id = tid + 256 * i;
      int rr = id >> 3, c = id & 7;
      *(half8*)&Ks[rr * 72 + c * 8] = *(const half8*)&kbh[(size_t)(kt * 64 + rr) * HD + c * 8];
      *(half8*)&Vs[rr * 72 + c * 8] = *(const half8*)&vbh[((size_t)kt * 64 + rr) * 64 + c * 8];
    }
    __syncthreads();

    // S^T = K @ Q^T : sc[jj][r] = S[qrow=l16][kcol = jj*16+quad*4+r]
    floatx4 sc[4] = {};
#pragma unroll
    for (int jj = 0; jj < 4; ++jj) {
#pragma unroll
      for (int ks = 0; ks < 2; ++ks) {
        half8 ak = *(const half8*)&Ks[(jj * 16 + l16) * 72 + ks * 32 + quad * 8];
        sc[jj] = __builtin_amdgcn_mfma_f32_16x16x32_f16(ak, aq[ks], sc[jj], 0, 0, 0);
      }
    }

    // online softmax, one Q-row per lane (log2 domain; scale pre-folded)
    float mx = -INFINITY;
#pragma unroll
    for (int jj = 0; jj < 4; ++jj)
#pragma unroll
      for (int r = 0; r < 4; ++r) mx = fmaxf(mx, sc[jj][r]);
    mx = fmaxf(mx, __shfl_xor(mx, 16));
    mx = fmaxf(mx, __shfl_xor(mx, 32));
    const float mn = fmaxf(mrow, mx);
    const float alpha = exp2f(mrow - mn);
    mrow = mn;

    float rs = 0.f;
    half4v ap[4];
#pragma unroll
    for (int jj = 0; jj < 4; ++jj) {
#pragma unroll
      for (int r = 0; r < 4; ++r) {
        float p = exp2f(sc[jj][r] - mn);
        rs += p;
        ap[jj][r] = (_Float16)p;
      }
    }
    rs += __shfl_xor(rs, 16);
    rs += __shfl_xor(rs, 32);
    lrow = lrow * alpha + rs;

    // rescale O (O rows live at qrow = quad*4+r; alpha lives at qrow = l16)
    float alr[4];
#pragma unroll
    for (int r = 0; r < 4; ++r) alr[r] = __shfl(alpha, quad * 4 + r);
#pragma unroll
    for (int jb = 0; jb < 4; ++jb)
#pragma unroll
      for (int r = 0; r < 4; ++r) o16[jb][r] *= alr[r];

    // O += P @ V : 16x16x16 MFMAs, P (ap) direct from registers.
#pragma unroll
    for (int jb = 0; jb < 4; ++jb) {
      half8 v01 = *(const half8*)&Vs[(jb * 16 + l16) * 72 + quad * 16];
      half8 v23 = *(const half8*)&Vs[(jb * 16 + l16) * 72 + quad * 16 + 8];
      half4v b0 = __builtin_shufflevector(v01, v01, 0, 1, 2, 3);
      half4v b1 = __builtin_shufflevector(v01, v01, 4, 5, 6, 7);
      half4v b2 = __builtin_shufflevector(v23, v23, 0, 1, 2, 3);
      half4v b3 = __builtin_shufflevector(v23, v23, 4, 5, 6, 7);
      o16[jb] = MFMA16(ap[0], b0, o16[jb]);
      o16[jb] = MFMA16(ap[1], b1, o16[jb]);
      o16[jb] = MFMA16(ap[2], b2, o16[jb]);
      o16[jb] = MFMA16(ap[3], b3, o16[jb]);
    }
  }

  // epilogue: divide by l (broadcast to O layout) and store
  float linv[4];
#pragma unroll
  for (int r = 0; r < 4; ++r) linv[r] = 1.0f / __shfl(lrow, quad * 4 + r);
#pragma unroll
  for (int jb = 0; jb < 4; ++jb) {
#pragma unroll
    for (int r = 0; r < 4; ++r) {
      const int row = q0 + wave * 16 + quad * 4 + r;
      out[(size_t)(b * S + row) * INNER + h * HD + jb * 16 + l16] =
          (_Float16)(o16[jb][r] * linv[r]);
    }
  }
}

// ---------------------------------------------------------------------------
extern "C" void kernel_launch(void* const* d_in, const int* in_sizes, int n_in,
                              void* d_out, int out_size, void* d_ws, size_t ws_size,
                              hipStream_t stream) {
  const float* hs    = (const float*)d_in[0];
  const float* rot   = (const float*)d_in[1];
  const float* w_qkv = (const float*)d_in[2];
  const float* b_qkv = (const float*)d_in[3];
  const float* nqw   = (const float*)d_in[4];
  const float* nkw   = (const float*)d_in[5];
  const float* w_out = (const float*)d_in[6];
  const float* b_out = (const float*)d_in[7];
  const float* hks   = (const float*)d_in[8];
  const int*   octx  = (const int*)d_in[9];

  _Float16* hsb   = (_Float16*)d_ws;                 // 4096x1024 f16 (8 MiB)
  _Float16* attnb = hsb;                             // alias: hsb dead after QKV GEMM
  _Float16* wqkvT = hsb   + (size_t)NTOK * DIM;      // 3072x1024 (6 MiB)
  _Float16* woutT = wqkvT + (size_t)QKVN * DIM;      // 1024x1024 (2 MiB)
  _Float16* qkvh  = woutT + (size_t)DIM * INNER;     // 4096x3072 (24 MiB)
  _Float16* q_h   = qkvh  + (size_t)NTOK * QKVN;     // [2][16][2048][64] (8 MiB)
  _Float16* k_h   = q_h   + (size_t)B * NH * S * HD; // (8 MiB)
  _Float16* vT    = k_h   + (size_t)B * NH * S * HD; // swizzled (8 MiB)

  cvt_f16<<<(NTOK * DIM / 8 + 255) / 256, 256, 0, stream>>>(hs, hsb, NTOK * DIM / 8);
  transpose_w<<<dim3(QKVN / 64, DIM / 64), 256, 0, stream>>>(w_qkv, wqkvT, DIM, QKVN);
  transpose_w<<<dim3(DIM / 64, INNER / 64), 256, 0, stream>>>(w_out, woutT, INNER, DIM);

  gemm_bt<true, _Float16><<<dim3(QKVN / 128, NTOK / 128), 256, 0, stream>>>(
      hsb, wqkvT, b_qkv, qkvh, QKVN, DIM);

  postprocess<<<NTOK, 256, 0, stream>>>(qkvh, rot, nqw, nkw, hks, octx, q_h, k_h);
  prep_vT<<<dim3(B * NH, S / 64), 256, 0, stream>>>(qkvh, vT);

  attn_mfma<<<dim3(B * NH, S / 64), 256, 0, stream>>>(q_h, k_h, vT, attnb);

  gemm_bt<false, float><<<dim3(DIM / 128, NTOK / 128), 256, 0, stream>>>(
      attnb, woutT, b_out, (float*)d_out, DIM, INNER);
}